// Round 6
// baseline (130.630 us; speedup 1.0000x reference)
//
#include <hip/hip_runtime.h>

// Fused 2-level inverse Haar DWT (UnPatcher, PATCH_SIZE=4), direct
// (no LDS), batch-fastest block swizzle to spread the 16-way
// plane-strided gather across HBM channels.
// Input  x:   [8, 256, 96, 96]  fp32
// Output out: [8, 16, 384, 384] fp32
//
// Block = 384 threads = (4 rows x 96 q) of one (b, g) tile.
// Thread (r, q): reads 16 scalars x[b, g+16k+64m, p0+r, q] (channel-strided
// gather, 384B-coalesced per wave-segment), applies the 2-level +/-1
// butterfly (per-level scale 2*S*S == 1), stores a 4x4 output tile as 4
// lane-contiguous dwordx4 (1KB contiguous per wave per store).
// Block order: b fastest, then g, then row-block -> concurrent waves read
// from 8 batches x different g, decorrelating the stride-589824 congruence.

#define B_   8
#define CIN  256
#define G_   16
#define H_   96
#define W_   96
#define OW   384
#define ROWS 4
#define NT_  (ROWS * W_)   // 384

__global__ __launch_bounds__(NT_, 8) void idwt2_direct_swz(const float* __restrict__ x,
                                                           float* __restrict__ out) {
    const int tid = threadIdx.x;
    int bid  = blockIdx.x;
    // batch-fastest swizzle
    int b    = bid & 7;            // bid % 8
    int t0   = bid >> 3;
    int g    = t0 & 15;            // % 16
    int pblk = t0 >> 4;            // 0..23
    int r    = tid / W_;           // 0..3
    int q    = tid % W_;           // 0..95
    int p    = pblk * ROWS + r;

    const size_t plane = (size_t)H_ * W_;  // 9216
    const float* xin = x + (size_t)b * CIN * plane + (size_t)p * W_ + q;

    // v[k][m] = x[b, g + 16k + 64m, p, q]
    float v[4][4];
#pragma unroll
    for (int k = 0; k < 4; ++k) {
#pragma unroll
        for (int m = 0; m < 4; ++m) {
            v[k][m] = xin[(size_t)(g + 16 * k + 64 * m) * plane];
        }
    }

    // Level 1 (inner, channel stride 64): t[k][2*dh+dw]
    float t[4][4];
#pragma unroll
    for (int k = 0; k < 4; ++k) {
        float u0 = v[k][0] + v[k][1];
        float u1 = v[k][0] - v[k][1];
        float u2 = v[k][2] + v[k][3];
        float u3 = v[k][2] - v[k][3];
        t[k][0] = u0 + u2;
        t[k][1] = u0 - u2;
        t[k][2] = u1 + u3;
        t[k][3] = u1 - u3;
    }

    // Level 2 (outer, channel stride 16)
    float rowv[4][4];
#pragma unroll
    for (int dh = 0; dh < 2; ++dh) {
#pragma unroll
        for (int dw = 0; dw < 2; ++dw) {
            int i = 2 * dh + dw;
            float a0 = t[0][i] + t[1][i];
            float a1 = t[0][i] - t[1][i];
            float a2 = t[2][i] + t[3][i];
            float a3 = t[2][i] - t[3][i];
            rowv[2 * dh + 0][2 * dw + 0] = a0 + a2;
            rowv[2 * dh + 0][2 * dw + 1] = a0 - a2;
            rowv[2 * dh + 1][2 * dw + 0] = a1 + a3;
            rowv[2 * dh + 1][2 * dw + 1] = a1 - a3;
        }
    }

    float* obase = out + ((size_t)(b * G_ + g) * OW + 4 * (size_t)p) * OW + 4 * (size_t)q;
#pragma unroll
    for (int rr = 0; rr < 4; ++rr) {
        float4 f4 = make_float4(rowv[rr][0], rowv[rr][1], rowv[rr][2], rowv[rr][3]);
        *reinterpret_cast<float4*>(obase + (size_t)rr * OW) = f4;
    }
}

extern "C" void kernel_launch(void* const* d_in, const int* in_sizes, int n_in,
                              void* d_out, int out_size, void* d_ws, size_t ws_size,
                              hipStream_t stream) {
    const float* x = (const float*)d_in[0];
    float* out = (float*)d_out;
    const int grid = B_ * G_ * (H_ / ROWS);  // 3072
    idwt2_direct_swz<<<grid, NT_, 0, stream>>>(x, out);
}